// Round 2
// baseline (172.715 us; speedup 1.0000x reference)
//
#include <hip/hip_runtime.h>
#include <stdint.h>
#include <stddef.h>

// Problem constants (match reference setup_inputs)
static constexpr int Bb = 2;      // batch
static constexpr int Mq = 4096;   // queries per batch
static constexpr int Cc = 256;    // channels (GEMM K)
static constexpr int Hh = 64, Ww = 64;
static constexpr int Np = Hh * Ww;     // 4096 pixels
static constexpr int NL1 = 1024;       // 32*32 pooled (level-1) pixels
static constexpr int RAD = 4;
static constexpr int SIDE = 2 * RAD + 1;     // 9
static constexpr int KPL = SIDE * SIDE;      // 81
static constexpr int NLVL = 4;
static constexpr int KTOT = NLVL * KPL;      // 324

// Workspace layout (bytes)
static constexpr size_t L1BUF_B  = 0;                                    // 16.8 MB bf16
static constexpr size_t WINBUF_B = (size_t)Bb * Mq * 1024 * 2;           // +3.3 MB fp32
static constexpr size_t ABF_B    = WINBUF_B + (size_t)Bb * Mq * 100 * 4; // +4.2 MB bf16
static constexpr size_t BT_B     = ABF_B + (size_t)Bb * Mq * Cc * 2;     // +4.2 MB bf16
static constexpr size_t B1T_B    = BT_B + (size_t)Bb * Np * Cc * 2;      // +1.05 MB bf16

typedef float floatx4 __attribute__((ext_vector_type(4)));
typedef short shortx8 __attribute__((ext_vector_type(8)));

union BfPack {
    shortx8 v;
    unsigned short u[8];
};

// fp32 -> bf16 round-to-nearest-even (finite inputs only)
__device__ __forceinline__ unsigned short f2bf(float f) {
    unsigned int x = __float_as_uint(f);
    x += 0x7fffu + ((x >> 16) & 1u);
    return (unsigned short)(x >> 16);
}

__device__ __forceinline__ float bf2f(unsigned short u) {
    return __uint_as_float((unsigned int)u << 16);
}

// async global->LDS, 16 B per lane; LDS dest = base + lane*16 (wave-uniform base)
__device__ __forceinline__ void gll16(const void* g, void* l) {
    __builtin_amdgcn_global_load_lds(
        (const __attribute__((address_space(1))) unsigned int*)g,
        (__attribute__((address_space(3))) unsigned int*)l, 16, 0, 0);
}

// ---------------------------------------------------------------------------
// Merged prep:
//   blocks [0,1024)    : fmap1 fp32 -> Abf bf16 (same layout)
//   blocks [1024,1280) : fmap2 (b,c,p) -> Bt (b,p,c) bf16  AND
//                        2x2-pooled B1t (b, y1*32+x1, c) bf16.
// ---------------------------------------------------------------------------
__global__ __launch_bounds__(256)
void cvt_kernel(const float* __restrict__ f1, const float* __restrict__ f2,
                unsigned short* __restrict__ Abf, unsigned short* __restrict__ Bt,
                unsigned short* __restrict__ B1t)
{
    __shared__ float tile[64 * 132];   // [channel][2 rows * 64 px], pad 132
    const int tid = threadIdx.x;
    if (blockIdx.x < 1024) {
        const int t = blockIdx.x * 256 + tid;      // 262144 threads x 8 elems
        const float4 v0 = *(const float4*)(f1 + (size_t)t * 8);
        const float4 v1 = *(const float4*)(f1 + (size_t)t * 8 + 4);
        BfPack p;
        p.u[0] = f2bf(v0.x); p.u[1] = f2bf(v0.y);
        p.u[2] = f2bf(v0.z); p.u[3] = f2bf(v0.w);
        p.u[4] = f2bf(v1.x); p.u[5] = f2bf(v1.y);
        p.u[6] = f2bf(v1.z); p.u[7] = f2bf(v1.w);
        *(shortx8*)(Abf + (size_t)t * 8) = p.v;
        return;
    }
    const int bid  = blockIdx.x - 1024;            // 0..255
    const int b    = bid >> 7;                     // batch
    const int cblk = (bid >> 5) & 3;               // 64-channel block
    const int y1   = bid & 31;                     // pooled row = image rows 2y1,2y1+1

    // load 64 channels x 128 px (rows 2y1, 2y1+1), coalesced along p
#pragma unroll
    for (int i = 0; i < 8; ++i) {
        const int v  = i * 256 + tid;              // 0..2047 float4 slots
        const int c  = v >> 5;                     // 0..63
        const int f4 = v & 31;                     // 0..31
        *(float4*)&tile[c * 132 + f4 * 4] =
            *(const float4*)&f2[((size_t)(b * Cc + cblk * 64 + c)) * Np + y1 * 128 + f4 * 4];
    }
    __syncthreads();

    // Bt: full-res transpose, 16 B bf16 per write
#pragma unroll
    for (int i = 0; i < 4; ++i) {
        const int w  = i * 256 + tid;
        const int rp = w >> 3;                     // 0..127 (px within row pair)
        const int cg = w & 7;
        BfPack p;
#pragma unroll
        for (int u = 0; u < 8; ++u)
            p.u[u] = f2bf(tile[(cg * 8 + u) * 132 + rp]);
        *(shortx8*)&Bt[((size_t)(b * Np + y1 * 128 + rp)) * Cc + cblk * 64 + cg * 8] = p.v;
    }

    // B1t: 2x2 pooled transpose (pooling commutes with the channel contraction)
    {
        const int x1 = tid >> 3;                   // 0..31
        const int cg = tid & 7;
        BfPack p;
#pragma unroll
        for (int u = 0; u < 8; ++u) {
            const int c = cg * 8 + u;
            const float v = 0.25f * (tile[c * 132 + 2 * x1]      + tile[c * 132 + 2 * x1 + 1]
                                   + tile[c * 132 + 64 + 2 * x1] + tile[c * 132 + 64 + 2 * x1 + 1]);
            p.u[u] = f2bf(v);
        }
        *(shortx8*)&B1t[((size_t)(b * NL1 + y1 * 32 + x1)) * Cc + cblk * 64 + cg * 8] = p.v;
    }
}

// ---------------------------------------------------------------------------
// Level-0 window dots, CELL-BINNED version.
// One block per (batch, 4x4 centroid cell): queries whose (x0,y0) fall in the
// cell need window pixels inside a 13x13 region -> stage it ONCE in LDS
// (86.5 KB bf16), build the query list by scanning cent (32 KB, L2-resident),
// then compute each query's 100 taps from LDS with the per-wave channel-split
// dot + butterfly reduce. Cuts Bt traffic ~420 MB -> ~44 MB.
// ---------------------------------------------------------------------------
__global__ __launch_bounds__(512)
void win_kernel(const unsigned short* __restrict__ Abf, // (Bb*Mq, Cc)
                const unsigned short* __restrict__ Bt,  // (Bb*Np, Cc)
                const float* __restrict__ cent,         // (Bb*Mq, 2)
                float* __restrict__ winbuf)             // (Bb*Mq, 100)
{
    __shared__ unsigned short reg[13 * 13 * 256];   // 86,528 B region (bf16)
    __shared__ int qlist[128];
    __shared__ int qcnt;

    const int tid  = threadIdx.x;
    const int b    = blockIdx.x >> 8;          // 256 cells per batch
    const int cell = blockIdx.x & 255;
    const int biny = cell >> 4;
    const int binx = cell & 15;
    // cell covers x0 in [4binx-4, 4binx-1]; window cols union = [4binx-4, 4binx+8]
    const int xmin = (4 * binx - 4) > 0 ? (4 * binx - 4) : 0;
    const int ymin = (4 * biny - 4) > 0 ? (4 * biny - 4) : 0;
    const int xmax = (4 * binx + 8) < 63 ? (4 * binx + 8) : 63;
    const int ymax = (4 * biny + 8) < 63 ? (4 * biny + 8) : 63;
    const int rh = ymax - ymin + 1;            // <= 13
    const int rw = xmax - xmin + 1;            // <= 13

    if (tid == 0) qcnt = 0;
    __syncthreads();

    // scan this batch's 4096 centroids for cell membership (binx = floor(cx)>>2)
#pragma unroll
    for (int i = 0; i < 8; ++i) {
        const int m = i * 512 + tid;
        const float2 cc = *(const float2*)&cent[((size_t)b * Mq + m) * 2];
        const int qbx = ((int)floorf(cc.x)) >> 2;
        const int qby = ((int)floorf(cc.y)) >> 2;
        if (qbx == binx && qby == biny) {
            const int idx = atomicAdd(&qcnt, 1);
            if (idx < 128) qlist[idx] = m;
        }
    }

    // stage region rows: row = rw*512 B contiguous span of Bt
    const int rw32 = rw * 32;                  // 16 B chunks per row (<= 416)
    for (int ry = 0; ry < rh; ++ry) {
        if (tid < rw32) {
            const size_t g = ((size_t)(b * Np) + (size_t)((ymin + ry) * Ww + xmin)) * Cc
                           + (size_t)tid * 8;
            *(shortx8*)&reg[(ry * 13) * 256 + tid * 8] = *(const shortx8*)&Bt[g];
        }
    }
    __syncthreads();

    const int cnt = qcnt < 128 ? qcnt : 128;
    const int wave = tid >> 6;
    const int lane = tid & 63;
    const int h    = lane >> 5;                // pixel parity within pair
    const int cl   = lane & 31;                // channel chunk (8 bf16 each)

    for (int qi = wave; qi < cnt; qi += 8) {
        const int m = qlist[qi];
        const size_t gq = (size_t)b * Mq + m;

        float a[8];
        {
            BfPack ap;
            ap.v = *(const shortx8*)&Abf[gq * Cc + cl * 8];
#pragma unroll
            for (int u = 0; u < 8; ++u) a[u] = bf2f(ap.u[u]);
        }
        const float2 cc = *(const float2*)&cent[gq * 2];
        const int x0 = (int)floorf(cc.x) - RAD;
        const int y0 = (int)floorf(cc.y) - RAD;

        for (int wy = 0; wy < 10; ++wy) {
            const int y = y0 + wy;
            if ((unsigned)y > 63u) continue;   // row outside image: taps never read
            const int rybase = ((y - ymin) * 13 - xmin) * 256;

            float acc0 = 0.f, acc1 = 0.f, acc2 = 0.f, acc3 = 0.f, acc4 = 0.f;
#pragma unroll
            for (int it = 0; it < 5; ++it) {
                const int p = it * 2 + h;
                const int x = x0 + p;
                if ((unsigned)x <= 63u) {
                    BfPack bv;
                    bv.v = *(const shortx8*)&reg[rybase + x * 256 + cl * 8];
                    float s = 0.f;
#pragma unroll
                    for (int u = 0; u < 8; ++u)
                        s = fmaf(a[u], bf2f(bv.u[u]), s);
                    if (it == 0) acc0 += s;
                    else if (it == 1) acc1 += s;
                    else if (it == 2) acc2 += s;
                    else if (it == 3) acc3 += s;
                    else acc4 += s;
                }
            }
            // butterfly reduce over the 32 channel-chunk lanes (stays within halves)
#pragma unroll
            for (int mm = 16; mm >= 1; mm >>= 1) {
                acc0 += __shfl_xor(acc0, mm);
                acc1 += __shfl_xor(acc1, mm);
                acc2 += __shfl_xor(acc2, mm);
                acc3 += __shfl_xor(acc3, mm);
                acc4 += __shfl_xor(acc4, mm);
            }
            float val = acc0;
            val = (cl == 1) ? acc1 : val;
            val = (cl == 2) ? acc2 : val;
            val = (cl == 3) ? acc3 : val;
            val = (cl == 4) ? acc4 : val;
            const int p = cl * 2 + h;
            const int x = x0 + p;
            if (cl < 5 && (unsigned)x <= 63u)
                winbuf[gq * 100 + wy * 10 + p] = val;
        }
    }
}

// ---------------------------------------------------------------------------
// Level-1 GEMM: L1[m, p1] = dot(Abf[m], B1t[p1])  (pooled-B trick).
// M=8192, N=1024, K=256. 128x128 dbuf global_load_lds K-loop with source-side
// XOR bank swizzle; epilogue is a plain LDS-transposed bf16 store of C.
// ---------------------------------------------------------------------------
__global__ __launch_bounds__(256)
void l1_gemm_kernel(const unsigned short* __restrict__ Abf, // (Bb*Mq, Cc)
                    const unsigned short* __restrict__ B1t, // (Bb*NL1, Cc)
                    unsigned short* __restrict__ l1buf)     // (Bb*Mq, 1024) bf16
{
    __shared__ union {
        unsigned short stage[2][2][128 * 32]; // [buf][a=0/b=1][row*32+k] 32 KB
        float corrT[32 * 132];                // epilogue staging
    } sm;

    const int b    = blockIdx.z;
    const int bm0  = blockIdx.y * 128;
    const int bn0  = blockIdx.x * 128;
    const int tid  = threadIdx.x;
    const int lane = tid & 63;
    const int wave = tid >> 6;
    const int lane15 = lane & 15;
    const int quad   = lane >> 4;
    const int wm = (wave >> 1) * 64;
    const int wn = (wave & 1) * 64;

    // staging addresses: one instr covers 16 rows; lane -> row lane/4,
    // SWIZZLED k-group (lane&3)^((row>>1)&3) so slot (r,g) = global (r,g^sig)
    const int lrow = lane >> 2;
    const int lkg  = (((lane & 3) ^ ((lrow >> 1) & 3))) * 8;
    const unsigned short* aptr = Abf + (size_t)(b * Mq + bm0 + wave * 16 + lrow) * Cc + lkg;
    const unsigned short* bptr = B1t + (size_t)(b * NL1 + bn0 + wave * 16 + lrow) * Cc + lkg;

    floatx4 acc[4][4];
#pragma unroll
    for (int i = 0; i < 4; ++i)
#pragma unroll
        for (int j = 0; j < 4; ++j)
            acc[i][j] = floatx4{0.0f, 0.0f, 0.0f, 0.0f};

    // prologue: stage k-tile 0 into buffer 0
    gll16(aptr,           &sm.stage[0][0][wave * 512]);
    gll16(aptr + 64 * Cc, &sm.stage[0][0][2048 + wave * 512]);
    gll16(bptr,           &sm.stage[0][1][wave * 512]);
    gll16(bptr + 64 * Cc, &sm.stage[0][1][2048 + wave * 512]);

    // reader-side swizzled k-group offset (row within 16-seg == lane15)
    const int rq = (quad ^ ((lane15 >> 1) & 3)) * 8;

    for (int k0 = 0; k0 < 8; ++k0) {
        __syncthreads();   // drains this wave's gll for buffer k0&1
        if (k0 < 7) {
            const int nb = (k0 + 1) & 1;
            const int ko = (k0 + 1) * 32;
            gll16(aptr + ko,           &sm.stage[nb][0][wave * 512]);
            gll16(aptr + 64 * Cc + ko, &sm.stage[nb][0][2048 + wave * 512]);
            gll16(bptr + ko,           &sm.stage[nb][1][wave * 512]);
            gll16(bptr + 64 * Cc + ko, &sm.stage[nb][1][2048 + wave * 512]);
        }
        const unsigned short* la = sm.stage[k0 & 1][0];
        const unsigned short* lb = sm.stage[k0 & 1][1];
        shortx8 af[4], bf[4];
#pragma unroll
        for (int i = 0; i < 4; ++i)
            af[i] = *(const shortx8*)&la[(wm + i * 16 + lane15) * 32 + rq];
#pragma unroll
        for (int j = 0; j < 4; ++j)
            bf[j] = *(const shortx8*)&lb[(wn + j * 16 + lane15) * 32 + rq];
#pragma unroll
        for (int i = 0; i < 4; ++i)
#pragma unroll
            for (int j = 0; j < 4; ++j)
                acc[i][j] = __builtin_amdgcn_mfma_f32_16x16x32_bf16(
                    af[i], bf[j], acc[i][j], 0, 0, 0);
    }

    // ---- epilogue: 4 chunks of 32 rows through LDS -> bf16 coalesced store ----
    // C/D layout: col = lane15, row = quad*4+reg (m89/m91 verified).
    float* corrT = sm.corrT;
    const int row = tid >> 3;   // 0..31
    const int g   = tid & 7;    // 0..7 -> 16-col group
#pragma unroll
    for (int c = 0; c < 4; ++c) {
        __syncthreads();
        if ((wave >> 1) == (c >> 1)) {
#pragma unroll
            for (int ii = 0; ii < 2; ++ii) {
                const int i = 2 * (c & 1) + ii;
#pragma unroll
                for (int j = 0; j < 4; ++j) {
#pragma unroll
                    for (int reg = 0; reg < 4; ++reg) {
                        const int rl = ii * 16 + quad * 4 + reg;
                        const int n  = wn + j * 16 + lane15;
                        corrT[rl * 132 + n] = acc[i][j][reg];
                    }
                }
            }
        }
        __syncthreads();

        const size_t gq = (size_t)(b * Mq + bm0 + 32 * c + row);
        const float* T = &corrT[row * 132];
        BfPack p0, p1;
#pragma unroll
        for (int u = 0; u < 8; ++u) {
            p0.u[u] = f2bf(T[g * 16 + u]);
            p1.u[u] = f2bf(T[g * 16 + 8 + u]);
        }
        *(shortx8*)&l1buf[gq * 1024 + bn0 + g * 16]     = p0.v;
        *(shortx8*)&l1buf[gq * 1024 + bn0 + g * 16 + 8] = p1.v;
    }
}

// ---------------------------------------------------------------------------
// Sampler: 8 queries/block. Loads L1 (2 KB bf16/query) + window (400 B/query),
// builds L2/L3 in LDS, emits all 324 outputs per query.  (unchanged)
// ---------------------------------------------------------------------------
__global__ __launch_bounds__(256)
void pyr_sample_kernel(const float* __restrict__ cent,           // (Bb*Mq, 2)
                       const unsigned short* __restrict__ l1buf, // (Bb*Mq, 1024) bf16
                       const float* __restrict__ winbuf,         // (Bb*Mq, 100)
                       float* __restrict__ out)                  // (Bb, 324, Mq)
{
    __shared__ float l1[8][1024];    // 32x32
    __shared__ float l2[8][256];     // 16x16
    __shared__ float l3[8][64];      // 8x8
    __shared__ float win0[8][100];   // 10x10 L0 window
    __shared__ float qcx[8], qcy[8];
    __shared__ int   qx0[8], qy0[8];

    const int tid = threadIdx.x;
    const int b   = blockIdx.x >> 9;           // 512 blocks per batch
    const int m0  = (blockIdx.x & 511) * 8;
    const size_t gq0 = (size_t)(b * Mq + m0);

    if (tid < 8) {
        const float cx = cent[(gq0 + tid) * 2 + 0];
        const float cy = cent[(gq0 + tid) * 2 + 1];
        qcx[tid] = cx; qcy[tid] = cy;
        qx0[tid] = (int)floorf(cx) - RAD;
        qy0[tid] = (int)floorf(cy) - RAD;
    }

    // load L1: 8 queries x 128 ushort8 (16 B) each -> expand bf16 to f32 LDS
#pragma unroll
    for (int it = 0; it < 4; ++it) {
        const int v = it * 256 + tid;          // ushort8 index, 0..1023
        const int q = v >> 7;
        const int o = v & 127;
        BfPack p;
        p.v = *(const shortx8*)&l1buf[(gq0 + q) * 1024 + o * 8];
#pragma unroll
        for (int u = 0; u < 8; ++u)
            l1[q][o * 8 + u] = bf2f(p.u[u]);
    }
    // load windows: 8 queries x 25 float4
    if (tid < 200) {
        const int q = tid / 25;
        const int o = tid - q * 25;
        *(float4*)&win0[q][o * 4] = *(const float4*)&winbuf[(gq0 + q) * 100 + o * 4];
    }
    __syncthreads();

    // L2 from L1
#pragma unroll
    for (int i = 0; i < 8; ++i) {
        const int idx = i * 256 + tid;
        const int q = idx >> 8;
        const int c = idx & 255;
        const int cy2 = c >> 4, cx2 = c & 15;
        const float* s = &l1[q][(2 * cy2) * 32 + 2 * cx2];
        l2[q][c] = 0.25f * (s[0] + s[1] + s[32] + s[33]);
    }
    __syncthreads();
    // L3 from L2
#pragma unroll
    for (int i = 0; i < 2; ++i) {
        const int idx = i * 256 + tid;
        const int q = idx >> 6;
        const int c = idx & 63;
        const int cy3 = c >> 3, cx3 = c & 7;
        const float* s = &l2[q][(2 * cy3) * 16 + 2 * cx3];
        l3[q][c] = 0.25f * (s[0] + s[1] + s[16] + s[17]);
    }
    __syncthreads();

    // sampling: 324*8 = 2592 outputs
    for (int i = 0; i < 11; ++i) {
        const int idx = i * 256 + tid;
        if (idx >= KTOT * 8) break;
        const int q  = idx & 7;
        const int kk = idx >> 3;           // 0..323
        const int lvl = kk / KPL;
        const int r   = kk - lvl * KPL;
        const int di  = r / SIDE;          // x-offset index
        const int dj  = r - di * SIDE;     // y-offset index

        const int w = Ww >> lvl;
        const float scale = 1.0f / (float)(1 << lvl);
        const float x = qcx[q] * scale + (float)(di - RAD);
        const float y = qcy[q] * scale + (float)(dj - RAD);

        const float x0f = floorf(x), y0f = floorf(y);
        const float wx1 = x - x0f, wx0 = 1.0f - wx1;
        const float wy1 = y - y0f, wy0 = 1.0f - wy1;
        const float fmx = (float)(w - 1);
        const bool vx0 = (x0f >= 0.0f) && (x0f <= fmx);
        const bool vx1 = (x0f + 1.0f >= 0.0f) && (x0f + 1.0f <= fmx);
        const bool vy0 = (y0f >= 0.0f) && (y0f <= fmx);
        const bool vy1 = (y0f + 1.0f >= 0.0f) && (y0f + 1.0f <= fmx);

        const int ix0 = (int)x0f, iy0 = (int)y0f;

        const float* buf;
        int stride, ox, oy;
        if (lvl == 0)      { buf = win0[q]; stride = 10; ox = qx0[q]; oy = qy0[q]; }
        else if (lvl == 1) { buf = l1[q];   stride = 32; ox = 0; oy = 0; }
        else if (lvl == 2) { buf = l2[q];   stride = 16; ox = 0; oy = 0; }
        else               { buf = l3[q];   stride =  8; ox = 0; oy = 0; }

        const int cx0 = ix0 - ox, cx1 = ix0 + 1 - ox;
        const int cy0r = iy0 - oy, cy1r = iy0 + 1 - oy;
        const float g00 = (vx0 && vy0) ? buf[cy0r * stride + cx0] : 0.0f;
        const float g10 = (vx1 && vy0) ? buf[cy0r * stride + cx1] : 0.0f;
        const float g01 = (vx0 && vy1) ? buf[cy1r * stride + cx0] : 0.0f;
        const float g11 = (vx1 && vy1) ? buf[cy1r * stride + cx1] : 0.0f;

        out[((size_t)b * KTOT + kk) * Mq + m0 + q] =
            wy0 * (wx0 * g00 + wx1 * g10) + wy1 * (wx0 * g01 + wx1 * g11);
    }
}

extern "C" void kernel_launch(void* const* d_in, const int* in_sizes, int n_in,
                              void* d_out, int out_size, void* d_ws, size_t ws_size,
                              hipStream_t stream)
{
    const float* fmap1 = (const float*)d_in[0];   // (Bb, Mq, Cc)
    const float* fmap2 = (const float*)d_in[1];   // (Bb, Cc, Hh, Ww)
    const float* cent  = (const float*)d_in[2];   // (Bb, Mq, 2)
    char* ws = (char*)d_ws;
    unsigned short* l1buf = (unsigned short*)(ws + L1BUF_B);
    float* winbuf = (float*)(ws + WINBUF_B);
    unsigned short* Abf = (unsigned short*)(ws + ABF_B);
    unsigned short* Bt  = (unsigned short*)(ws + BT_B);
    unsigned short* B1t = (unsigned short*)(ws + B1T_B);
    float* out = (float*)d_out;

    // 0) merged prep: A cvt (1024 blocks) + B transpose/cvt + pooled B1t (256)
    cvt_kernel<<<1280, 256, 0, stream>>>(fmap1, fmap2, Abf, Bt, B1t);

    // 1) level-0 window taps, cell-binned (13x13 region staged in LDS per block)
    win_kernel<<<Bb * 256, 512, 0, stream>>>(Abf, Bt, cent, winbuf);

    // 2) level-1 correlation GEMM on pooled features (4x fewer FLOPs)
    dim3 ggrid(NL1 / 128, Mq / 128, Bb);
    l1_gemm_kernel<<<ggrid, 256, 0, stream>>>(Abf, B1t, l1buf);

    // 3) pyramid completion (L2/L3 in LDS) + bilinear sampling
    const int nblk = Bb * Mq / 8;   // 1024
    pyr_sample_kernel<<<nblk, 256, 0, stream>>>(cent, l1buf, winbuf, out);
}

// Round 3
// 121.781 us; speedup vs baseline: 1.4182x; 1.4182x over previous
//
#include <hip/hip_runtime.h>
#include <stdint.h>
#include <stddef.h>

// Problem constants (match reference setup_inputs)
static constexpr int Bb = 2;      // batch
static constexpr int Mq = 4096;   // queries per batch
static constexpr int Cc = 256;    // channels (GEMM K)
static constexpr int Hh = 64, Ww = 64;
static constexpr int Np = Hh * Ww;     // 4096 pixels
static constexpr int NL1 = 1024;       // 32*32 pooled (level-1) pixels
static constexpr int RAD = 4;
static constexpr int SIDE = 2 * RAD + 1;     // 9
static constexpr int KPL = SIDE * SIDE;      // 81
static constexpr int NLVL = 4;
static constexpr int KTOT = NLVL * KPL;      // 324

// Workspace layout (bytes)
static constexpr size_t L1BUF_B  = 0;                                    // 16.8 MB bf16
static constexpr size_t WINBUF_B = (size_t)Bb * Mq * 1024 * 2;           // +3.3 MB fp32
static constexpr size_t ABF_B    = WINBUF_B + (size_t)Bb * Mq * 100 * 4; // +4.2 MB bf16
static constexpr size_t BT_B     = ABF_B + (size_t)Bb * Mq * Cc * 2;     // +4.2 MB bf16
static constexpr size_t B1T_B    = BT_B + (size_t)Bb * Np * Cc * 2;      // +1.05 MB bf16

typedef float floatx4 __attribute__((ext_vector_type(4)));
typedef short shortx8 __attribute__((ext_vector_type(8)));

union BfPack {
    shortx8 v;
    unsigned short u[8];
};

// fp32 -> bf16 round-to-nearest-even (finite inputs only)
__device__ __forceinline__ unsigned short f2bf(float f) {
    unsigned int x = __float_as_uint(f);
    x += 0x7fffu + ((x >> 16) & 1u);
    return (unsigned short)(x >> 16);
}

__device__ __forceinline__ float bf2f(unsigned short u) {
    return __uint_as_float((unsigned int)u << 16);
}

// async global->LDS, 16 B per lane; LDS dest = base + lane*16 (wave-uniform base)
__device__ __forceinline__ void gll16(const void* g, void* l) {
    __builtin_amdgcn_global_load_lds(
        (const __attribute__((address_space(1))) unsigned int*)g,
        (__attribute__((address_space(3))) unsigned int*)l, 16, 0, 0);
}

// ---------------------------------------------------------------------------
// Merged prep:
//   blocks [0,1024)    : fmap1 fp32 -> Abf bf16 (same layout)
//   blocks [1024,1280) : fmap2 (b,c,p) -> Bt (b,p,c) bf16  AND
//                        2x2-pooled B1t (b, y1*32+x1, c) bf16.
// ---------------------------------------------------------------------------
__global__ __launch_bounds__(256)
void cvt_kernel(const float* __restrict__ f1, const float* __restrict__ f2,
                unsigned short* __restrict__ Abf, unsigned short* __restrict__ Bt,
                unsigned short* __restrict__ B1t)
{
    __shared__ float tile[64 * 132];   // [channel][2 rows * 64 px], pad 132
    const int tid = threadIdx.x;
    if (blockIdx.x < 1024) {
        const int t = blockIdx.x * 256 + tid;      // 262144 threads x 8 elems
        const float4 v0 = *(const float4*)(f1 + (size_t)t * 8);
        const float4 v1 = *(const float4*)(f1 + (size_t)t * 8 + 4);
        BfPack p;
        p.u[0] = f2bf(v0.x); p.u[1] = f2bf(v0.y);
        p.u[2] = f2bf(v0.z); p.u[3] = f2bf(v0.w);
        p.u[4] = f2bf(v1.x); p.u[5] = f2bf(v1.y);
        p.u[6] = f2bf(v1.z); p.u[7] = f2bf(v1.w);
        *(shortx8*)(Abf + (size_t)t * 8) = p.v;
        return;
    }
    const int bid  = blockIdx.x - 1024;            // 0..255
    const int b    = bid >> 7;                     // batch
    const int cblk = (bid >> 5) & 3;               // 64-channel block
    const int y1   = bid & 31;                     // pooled row = image rows 2y1,2y1+1

    // load 64 channels x 128 px (rows 2y1, 2y1+1), coalesced along p
#pragma unroll
    for (int i = 0; i < 8; ++i) {
        const int v  = i * 256 + tid;              // 0..2047 float4 slots
        const int c  = v >> 5;                     // 0..63
        const int f4 = v & 31;                     // 0..31
        *(float4*)&tile[c * 132 + f4 * 4] =
            *(const float4*)&f2[((size_t)(b * Cc + cblk * 64 + c)) * Np + y1 * 128 + f4 * 4];
    }
    __syncthreads();

    // Bt: full-res transpose, 16 B bf16 per write
#pragma unroll
    for (int i = 0; i < 4; ++i) {
        const int w  = i * 256 + tid;
        const int rp = w >> 3;                     // 0..127 (px within row pair)
        const int cg = w & 7;
        BfPack p;
#pragma unroll
        for (int u = 0; u < 8; ++u)
            p.u[u] = f2bf(tile[(cg * 8 + u) * 132 + rp]);
        *(shortx8*)&Bt[((size_t)(b * Np + y1 * 128 + rp)) * Cc + cblk * 64 + cg * 8] = p.v;
    }

    // B1t: 2x2 pooled transpose (pooling commutes with the channel contraction)
    {
        const int x1 = tid >> 3;                   // 0..31
        const int cg = tid & 7;
        BfPack p;
#pragma unroll
        for (int u = 0; u < 8; ++u) {
            const int c = cg * 8 + u;
            const float v = 0.25f * (tile[c * 132 + 2 * x1]      + tile[c * 132 + 2 * x1 + 1]
                                   + tile[c * 132 + 64 + 2 * x1] + tile[c * 132 + 64 + 2 * x1 + 1]);
            p.u[u] = f2bf(v);
        }
        *(shortx8*)&B1t[((size_t)(b * NL1 + y1 * 32 + x1)) * Cc + cblk * 64 + cg * 8] = p.v;
    }
}

// ---------------------------------------------------------------------------
// Level-0 window dots, CELL-BINNED + MFMA version.
// One block per (batch, 4x4 centroid cell). The cell's windows live inside a
// 13x13 pixel region staged once in LDS ([ry*13+rx][264] shorts, pad 264 so
// B-fragment ds_read_b128 hits the 8-phase bank minimum). Queries are binned
// by scanning cent; then C[16q x 169px] = A x region^T via 16x16x32 bf16 MFMA
// (11 N-tiles x 8 K-steps per 16-query chunk, 8 waves). Epilogue scatters
// valid taps (0<=wy,wx<10) straight from accumulators into winbuf.
// ---------------------------------------------------------------------------
__global__ __launch_bounds__(512)
void win_kernel(const unsigned short* __restrict__ Abf, // (Bb*Mq, Cc)
                const unsigned short* __restrict__ Bt,  // (Bb*Np, Cc)
                const float* __restrict__ cent,         // (Bb*Mq, 2)
                float* __restrict__ winbuf)             // (Bb*Mq, 100)
{
    __shared__ unsigned short reg[176 * 264];  // 92,928 B region (bf16, 13-stride rows)
    __shared__ int qlist[128];
    __shared__ int qx0s[128], qy0s[128];
    __shared__ int qcnt;

    const int tid  = threadIdx.x;
    const int b    = blockIdx.x >> 8;          // 256 cells per batch
    const int cell = blockIdx.x & 255;
    const int biny = cell >> 4;
    const int binx = cell & 15;
    // cell covers x0 in [4binx-4, 4binx-1]; window cols union = [4binx-4, 4binx+8]
    const int xmin = (4 * binx - 4) > 0 ? (4 * binx - 4) : 0;
    const int ymin = (4 * biny - 4) > 0 ? (4 * biny - 4) : 0;
    const int xmax = (4 * binx + 8) < 63 ? (4 * binx + 8) : 63;
    const int ymax = (4 * biny + 8) < 63 ? (4 * biny + 8) : 63;
    const int rh = ymax - ymin + 1;            // <= 13
    const int rw = xmax - xmin + 1;            // <= 13

    if (tid == 0) qcnt = 0;
    __syncthreads();

    // scan this batch's 4096 centroids for cell membership (binx = floor(cx)>>2)
#pragma unroll
    for (int i = 0; i < 8; ++i) {
        const int m = i * 512 + tid;
        const float2 cc = *(const float2*)&cent[((size_t)b * Mq + m) * 2];
        const int fx = (int)floorf(cc.x);
        const int fy = (int)floorf(cc.y);
        if ((fx >> 2) == binx && (fy >> 2) == biny) {
            const int idx = atomicAdd(&qcnt, 1);
            if (idx < 128) {
                qlist[idx] = m;
                qx0s[idx] = fx - RAD;
                qy0s[idx] = fy - RAD;
            }
        }
    }

    // stage region: per region row, rw*512 B contiguous span of Bt -> 13-stride LDS
    for (int ry = 0; ry < rh; ++ry) {
        const size_t gbase = ((size_t)(b * Np) + (size_t)((ymin + ry) * Ww + xmin)) * Cc;
        const int nchunk = rw * 32;            // 16 B chunks (<= 416)
        if (tid < nchunk) {
            const int px = tid >> 5;
            const int g  = tid & 31;
            *(shortx8*)&reg[(ry * 13 + px) * 264 + g * 8] =
                *(const shortx8*)&Bt[gbase + (size_t)tid * 8];
        }
    }
    __syncthreads();

    const int cnt = qcnt < 128 ? qcnt : 128;
    const int wave   = tid >> 6;               // 0..7
    const int lane   = tid & 63;
    const int lane15 = lane & 15;
    const int quad   = lane >> 4;

    for (int m0 = 0; m0 < cnt; m0 += 16) {
        // A-fragment prefetch: lane15 -> query row, quad -> k-subchunk
        const int qidx = (m0 + lane15) < cnt ? (m0 + lane15) : (cnt - 1);
        const unsigned short* arow =
            Abf + (size_t)(b * Mq + qlist[qidx]) * Cc + quad * 8;
        shortx8 afr[8];
#pragma unroll
        for (int k0 = 0; k0 < 8; ++k0)
            afr[k0] = *(const shortx8*)&arow[k0 * 32];

        // N-tiles: jt0 = wave (0..7), jt1 = wave+8 (8..10, waves 0-2 only)
        const int jt0 = wave, jt1 = wave + 8;
        floatx4 acc0 = {0.f, 0.f, 0.f, 0.f};
        floatx4 acc1 = {0.f, 0.f, 0.f, 0.f};
#pragma unroll
        for (int k0 = 0; k0 < 8; ++k0) {
            const shortx8 b0 =
                *(const shortx8*)&reg[(jt0 * 16 + lane15) * 264 + k0 * 32 + quad * 8];
            acc0 = __builtin_amdgcn_mfma_f32_16x16x32_bf16(afr[k0], b0, acc0, 0, 0, 0);
            if (wave < 3) {
                const shortx8 b1 =
                    *(const shortx8*)&reg[(jt1 * 16 + lane15) * 264 + k0 * 32 + quad * 8];
                acc1 = __builtin_amdgcn_mfma_f32_16x16x32_bf16(afr[k0], b1, acc1, 0, 0, 0);
            }
        }

        // scatter: C layout col=lane15, row=quad*4+reg (m89/m91 verified)
#pragma unroll
        for (int t = 0; t < 2; ++t) {
            if (t == 1 && wave >= 3) break;
            const int jt = (t == 0) ? jt0 : jt1;
            const floatx4 a = (t == 0) ? acc0 : acc1;
            const int col = jt * 16 + lane15;
            const int py = col / 13;
            const int px = col - py * 13;
            if (py < rh && px < rw) {
                const int y = ymin + py, x = xmin + px;
#pragma unroll
                for (int r = 0; r < 4; ++r) {
                    const int qi = m0 + quad * 4 + r;
                    if (qi < cnt) {
                        const int wy = y - qy0s[qi];
                        const int wx = x - qx0s[qi];
                        if ((unsigned)wy < 10u && (unsigned)wx < 10u)
                            winbuf[((size_t)b * Mq + qlist[qi]) * 100 + wy * 10 + wx] = a[r];
                    }
                }
            }
        }
    }
}

// ---------------------------------------------------------------------------
// Level-1 GEMM: L1[m, p1] = dot(Abf[m], B1t[p1])  (pooled-B trick).
// M=8192, N=1024, K=256. 128x128 dbuf global_load_lds K-loop with source-side
// XOR bank swizzle; epilogue is a plain LDS-transposed bf16 store of C.
// ---------------------------------------------------------------------------
__global__ __launch_bounds__(256)
void l1_gemm_kernel(const unsigned short* __restrict__ Abf, // (Bb*Mq, Cc)
                    const unsigned short* __restrict__ B1t, // (Bb*NL1, Cc)
                    unsigned short* __restrict__ l1buf)     // (Bb*Mq, 1024) bf16
{
    __shared__ union {
        unsigned short stage[2][2][128 * 32]; // [buf][a=0/b=1][row*32+k] 32 KB
        float corrT[32 * 132];                // epilogue staging
    } sm;

    const int b    = blockIdx.z;
    const int bm0  = blockIdx.y * 128;
    const int bn0  = blockIdx.x * 128;
    const int tid  = threadIdx.x;
    const int lane = tid & 63;
    const int wave = tid >> 6;
    const int lane15 = lane & 15;
    const int quad   = lane >> 4;
    const int wm = (wave >> 1) * 64;
    const int wn = (wave & 1) * 64;

    // staging addresses: one instr covers 16 rows; lane -> row lane/4,
    // SWIZZLED k-group (lane&3)^((row>>1)&3) so slot (r,g) = global (r,g^sig)
    const int lrow = lane >> 2;
    const int lkg  = (((lane & 3) ^ ((lrow >> 1) & 3))) * 8;
    const unsigned short* aptr = Abf + (size_t)(b * Mq + bm0 + wave * 16 + lrow) * Cc + lkg;
    const unsigned short* bptr = B1t + (size_t)(b * NL1 + bn0 + wave * 16 + lrow) * Cc + lkg;

    floatx4 acc[4][4];
#pragma unroll
    for (int i = 0; i < 4; ++i)
#pragma unroll
        for (int j = 0; j < 4; ++j)
            acc[i][j] = floatx4{0.0f, 0.0f, 0.0f, 0.0f};

    // prologue: stage k-tile 0 into buffer 0
    gll16(aptr,           &sm.stage[0][0][wave * 512]);
    gll16(aptr + 64 * Cc, &sm.stage[0][0][2048 + wave * 512]);
    gll16(bptr,           &sm.stage[0][1][wave * 512]);
    gll16(bptr + 64 * Cc, &sm.stage[0][1][2048 + wave * 512]);

    // reader-side swizzled k-group offset (row within 16-seg == lane15)
    const int rq = (quad ^ ((lane15 >> 1) & 3)) * 8;

    for (int k0 = 0; k0 < 8; ++k0) {
        __syncthreads();   // drains this wave's gll for buffer k0&1
        if (k0 < 7) {
            const int nb = (k0 + 1) & 1;
            const int ko = (k0 + 1) * 32;
            gll16(aptr + ko,           &sm.stage[nb][0][wave * 512]);
            gll16(aptr + 64 * Cc + ko, &sm.stage[nb][0][2048 + wave * 512]);
            gll16(bptr + ko,           &sm.stage[nb][1][wave * 512]);
            gll16(bptr + 64 * Cc + ko, &sm.stage[nb][1][2048 + wave * 512]);
        }
        const unsigned short* la = sm.stage[k0 & 1][0];
        const unsigned short* lb = sm.stage[k0 & 1][1];
        shortx8 af[4], bf[4];
#pragma unroll
        for (int i = 0; i < 4; ++i)
            af[i] = *(const shortx8*)&la[(wm + i * 16 + lane15) * 32 + rq];
#pragma unroll
        for (int j = 0; j < 4; ++j)
            bf[j] = *(const shortx8*)&lb[(wn + j * 16 + lane15) * 32 + rq];
#pragma unroll
        for (int i = 0; i < 4; ++i)
#pragma unroll
            for (int j = 0; j < 4; ++j)
                acc[i][j] = __builtin_amdgcn_mfma_f32_16x16x32_bf16(
                    af[i], bf[j], acc[i][j], 0, 0, 0);
    }

    // ---- epilogue: 4 chunks of 32 rows through LDS -> bf16 coalesced store ----
    // C/D layout: col = lane15, row = quad*4+reg (m89/m91 verified).
    float* corrT = sm.corrT;
    const int row = tid >> 3;   // 0..31
    const int g   = tid & 7;    // 0..7 -> 16-col group
#pragma unroll
    for (int c = 0; c < 4; ++c) {
        __syncthreads();
        if ((wave >> 1) == (c >> 1)) {
#pragma unroll
            for (int ii = 0; ii < 2; ++ii) {
                const int i = 2 * (c & 1) + ii;
#pragma unroll
                for (int j = 0; j < 4; ++j) {
#pragma unroll
                    for (int reg = 0; reg < 4; ++reg) {
                        const int rl = ii * 16 + quad * 4 + reg;
                        const int n  = wn + j * 16 + lane15;
                        corrT[rl * 132 + n] = acc[i][j][reg];
                    }
                }
            }
        }
        __syncthreads();

        const size_t gq = (size_t)(b * Mq + bm0 + 32 * c + row);
        const float* T = &corrT[row * 132];
        BfPack p0, p1;
#pragma unroll
        for (int u = 0; u < 8; ++u) {
            p0.u[u] = f2bf(T[g * 16 + u]);
            p1.u[u] = f2bf(T[g * 16 + 8 + u]);
        }
        *(shortx8*)&l1buf[gq * 1024 + bn0 + g * 16]     = p0.v;
        *(shortx8*)&l1buf[gq * 1024 + bn0 + g * 16 + 8] = p1.v;
    }
}

// ---------------------------------------------------------------------------
// Sampler: 8 queries/block. Loads L1 (2 KB bf16/query) + window (400 B/query),
// builds L2/L3 in LDS, emits all 324 outputs per query.  (unchanged)
// ---------------------------------------------------------------------------
__global__ __launch_bounds__(256)
void pyr_sample_kernel(const float* __restrict__ cent,           // (Bb*Mq, 2)
                       const unsigned short* __restrict__ l1buf, // (Bb*Mq, 1024) bf16
                       const float* __restrict__ winbuf,         // (Bb*Mq, 100)
                       float* __restrict__ out)                  // (Bb, 324, Mq)
{
    __shared__ float l1[8][1024];    // 32x32
    __shared__ float l2[8][256];     // 16x16
    __shared__ float l3[8][64];      // 8x8
    __shared__ float win0[8][100];   // 10x10 L0 window
    __shared__ float qcx[8], qcy[8];
    __shared__ int   qx0[8], qy0[8];

    const int tid = threadIdx.x;
    const int b   = blockIdx.x >> 9;           // 512 blocks per batch
    const int m0  = (blockIdx.x & 511) * 8;
    const size_t gq0 = (size_t)(b * Mq + m0);

    if (tid < 8) {
        const float cx = cent[(gq0 + tid) * 2 + 0];
        const float cy = cent[(gq0 + tid) * 2 + 1];
        qcx[tid] = cx; qcy[tid] = cy;
        qx0[tid] = (int)floorf(cx) - RAD;
        qy0[tid] = (int)floorf(cy) - RAD;
    }

    // load L1: 8 queries x 128 ushort8 (16 B) each -> expand bf16 to f32 LDS
#pragma unroll
    for (int it = 0; it < 4; ++it) {
        const int v = it * 256 + tid;          // ushort8 index, 0..1023
        const int q = v >> 7;
        const int o = v & 127;
        BfPack p;
        p.v = *(const shortx8*)&l1buf[(gq0 + q) * 1024 + o * 8];
#pragma unroll
        for (int u = 0; u < 8; ++u)
            l1[q][o * 8 + u] = bf2f(p.u[u]);
    }
    // load windows: 8 queries x 25 float4
    if (tid < 200) {
        const int q = tid / 25;
        const int o = tid - q * 25;
        *(float4*)&win0[q][o * 4] = *(const float4*)&winbuf[(gq0 + q) * 100 + o * 4];
    }
    __syncthreads();

    // L2 from L1
#pragma unroll
    for (int i = 0; i < 8; ++i) {
        const int idx = i * 256 + tid;
        const int q = idx >> 8;
        const int c = idx & 255;
        const int cy2 = c >> 4, cx2 = c & 15;
        const float* s = &l1[q][(2 * cy2) * 32 + 2 * cx2];
        l2[q][c] = 0.25f * (s[0] + s[1] + s[32] + s[33]);
    }
    __syncthreads();
    // L3 from L2
#pragma unroll
    for (int i = 0; i < 2; ++i) {
        const int idx = i * 256 + tid;
        const int q = idx >> 6;
        const int c = idx & 63;
        const int cy3 = c >> 3, cx3 = c & 7;
        const float* s = &l2[q][(2 * cy3) * 16 + 2 * cx3];
        l3[q][c] = 0.25f * (s[0] + s[1] + s[16] + s[17]);
    }
    __syncthreads();

    // sampling: 324*8 = 2592 outputs
    for (int i = 0; i < 11; ++i) {
        const int idx = i * 256 + tid;
        if (idx >= KTOT * 8) break;
        const int q  = idx & 7;
        const int kk = idx >> 3;           // 0..323
        const int lvl = kk / KPL;
        const int r   = kk - lvl * KPL;
        const int di  = r / SIDE;          // x-offset index
        const int dj  = r - di * SIDE;     // y-offset index

        const int w = Ww >> lvl;
        const float scale = 1.0f / (float)(1 << lvl);
        const float x = qcx[q] * scale + (float)(di - RAD);
        const float y = qcy[q] * scale + (float)(dj - RAD);

        const float x0f = floorf(x), y0f = floorf(y);
        const float wx1 = x - x0f, wx0 = 1.0f - wx1;
        const float wy1 = y - y0f, wy0 = 1.0f - wy1;
        const float fmx = (float)(w - 1);
        const bool vx0 = (x0f >= 0.0f) && (x0f <= fmx);
        const bool vx1 = (x0f + 1.0f >= 0.0f) && (x0f + 1.0f <= fmx);
        const bool vy0 = (y0f >= 0.0f) && (y0f <= fmx);
        const bool vy1 = (y0f + 1.0f >= 0.0f) && (y0f + 1.0f <= fmx);

        const int ix0 = (int)x0f, iy0 = (int)y0f;

        const float* buf;
        int stride, ox, oy;
        if (lvl == 0)      { buf = win0[q]; stride = 10; ox = qx0[q]; oy = qy0[q]; }
        else if (lvl == 1) { buf = l1[q];   stride = 32; ox = 0; oy = 0; }
        else if (lvl == 2) { buf = l2[q];   stride = 16; ox = 0; oy = 0; }
        else               { buf = l3[q];   stride =  8; ox = 0; oy = 0; }

        const int cx0 = ix0 - ox, cx1 = ix0 + 1 - ox;
        const int cy0r = iy0 - oy, cy1r = iy0 + 1 - oy;
        const float g00 = (vx0 && vy0) ? buf[cy0r * stride + cx0] : 0.0f;
        const float g10 = (vx1 && vy0) ? buf[cy0r * stride + cx1] : 0.0f;
        const float g01 = (vx0 && vy1) ? buf[cy1r * stride + cx0] : 0.0f;
        const float g11 = (vx1 && vy1) ? buf[cy1r * stride + cx1] : 0.0f;

        out[((size_t)b * KTOT + kk) * Mq + m0 + q] =
            wy0 * (wx0 * g00 + wx1 * g10) + wy1 * (wx0 * g01 + wx1 * g11);
    }
}

extern "C" void kernel_launch(void* const* d_in, const int* in_sizes, int n_in,
                              void* d_out, int out_size, void* d_ws, size_t ws_size,
                              hipStream_t stream)
{
    const float* fmap1 = (const float*)d_in[0];   // (Bb, Mq, Cc)
    const float* fmap2 = (const float*)d_in[1];   // (Bb, Cc, Hh, Ww)
    const float* cent  = (const float*)d_in[2];   // (Bb, Mq, 2)
    char* ws = (char*)d_ws;
    unsigned short* l1buf = (unsigned short*)(ws + L1BUF_B);
    float* winbuf = (float*)(ws + WINBUF_B);
    unsigned short* Abf = (unsigned short*)(ws + ABF_B);
    unsigned short* Bt  = (unsigned short*)(ws + BT_B);
    unsigned short* B1t = (unsigned short*)(ws + B1T_B);
    float* out = (float*)d_out;

    // 0) merged prep: A cvt (1024 blocks) + B transpose/cvt + pooled B1t (256)
    cvt_kernel<<<1280, 256, 0, stream>>>(fmap1, fmap2, Abf, Bt, B1t);

    // 1) level-0 window taps, cell-binned MFMA (13x13 region staged in LDS)
    win_kernel<<<Bb * 256, 512, 0, stream>>>(Abf, Bt, cent, winbuf);

    // 2) level-1 correlation GEMM on pooled features (4x fewer FLOPs)
    dim3 ggrid(NL1 / 128, Mq / 128, Bb);
    l1_gemm_kernel<<<ggrid, 256, 0, stream>>>(Abf, B1t, l1buf);

    // 3) pyramid completion (L2/L3 in LDS) + bilinear sampling
    const int nblk = Bb * Mq / 8;   // 1024
    pyr_sample_kernel<<<nblk, 256, 0, stream>>>(cent, l1buf, winbuf, out);
}